// Round 3
// baseline (1107.711 us; speedup 1.0000x reference)
//
#include <hip/hip_runtime.h>
#include <math.h>

#define DM   2048
#define DFF  8192
#define NH   16
#define HD   128
#define SEQ  2048
#define MROWS 4096   // BATCH * SEQ

typedef __attribute__((ext_vector_type(4))) float  f32x4;
typedef __attribute__((ext_vector_type(8))) __bf16 bf16x8;
typedef __attribute__((ext_vector_type(4))) short  short4_t;

__device__ inline unsigned short f2bf(float f) {
  union { float f; unsigned int u; } x; x.f = f;
  unsigned int r = x.u + 0x7FFFu + ((x.u >> 16) & 1u);
  return (unsigned short)(r >> 16);
}

__device__ inline void gload16(const void* g, void* l) {
  __builtin_amdgcn_global_load_lds(
      (const __attribute__((address_space(1))) unsigned int*)g,
      (__attribute__((address_space(3))) unsigned int*)l, 16, 0, 0);
}

// ---------------- LayerNorm (f32 in, bf16 out) ----------------
__global__ __launch_bounds__(256) void ln_kernel(
    const float* __restrict__ in, const float* __restrict__ gw,
    const float* __restrict__ bw, unsigned short* __restrict__ out)
{
  const int row = blockIdx.x;
  const float* xr = in + (size_t)row * DM;
  const int t = threadIdx.x, lane = t & 63, w = t >> 6;
  float4 v0 = ((const float4*)xr)[t];
  float4 v1 = ((const float4*)xr)[t + 256];
  float s = v0.x+v0.y+v0.z+v0.w + v1.x+v1.y+v1.z+v1.w;
  float s2 = v0.x*v0.x+v0.y*v0.y+v0.z*v0.z+v0.w*v0.w
           + v1.x*v1.x+v1.y*v1.y+v1.z*v1.z+v1.w*v1.w;
  #pragma unroll
  for (int off = 32; off; off >>= 1) { s += __shfl_xor(s, off); s2 += __shfl_xor(s2, off); }
  __shared__ float rs[4], rs2[4];
  if (lane == 0) { rs[w] = s; rs2[w] = s2; }
  __syncthreads();
  s = rs[0] + rs[1] + rs[2] + rs[3];
  s2 = rs2[0] + rs2[1] + rs2[2] + rs2[3];
  const float mu = s * (1.0f / DM);
  const float var = s2 * (1.0f / DM) - mu * mu;
  const float rstd = rsqrtf(var + 1e-5f);
  float4 g0 = ((const float4*)gw)[t],     b0 = ((const float4*)bw)[t];
  float4 g1 = ((const float4*)gw)[t+256], b1 = ((const float4*)bw)[t+256];
  unsigned short* o = out + (size_t)row * DM;
  int i0 = t * 4, i1 = (t + 256) * 4;
  o[i0+0] = f2bf((v0.x-mu)*rstd*g0.x + b0.x);
  o[i0+1] = f2bf((v0.y-mu)*rstd*g0.y + b0.y);
  o[i0+2] = f2bf((v0.z-mu)*rstd*g0.z + b0.z);
  o[i0+3] = f2bf((v0.w-mu)*rstd*g0.w + b0.w);
  o[i1+0] = f2bf((v1.x-mu)*rstd*g1.x + b1.x);
  o[i1+1] = f2bf((v1.y-mu)*rstd*g1.y + b1.y);
  o[i1+2] = f2bf((v1.z-mu)*rstd*g1.z + b1.z);
  o[i1+3] = f2bf((v1.w-mu)*rstd*g1.w + b1.w);
}

// ------- weight transpose + f32->bf16: in[nrows][ncols] -> out[ncols][nrows] -------
__global__ void transpose_kernel(const float* __restrict__ in,
                                 unsigned short* __restrict__ out,
                                 int nrows, int ncols)
{
  __shared__ float tile[32][33];
  const int bx = blockIdx.x * 32;  // col base
  const int by = blockIdx.y * 32;  // row base
  const int tx = threadIdx.x, ty = threadIdx.y;
  #pragma unroll
  for (int i = ty; i < 32; i += 8)
    tile[i][tx] = in[(size_t)(by + i) * ncols + bx + tx];
  __syncthreads();
  #pragma unroll
  for (int i = ty; i < 32; i += 8)
    out[(size_t)(bx + i) * nrows + by + tx] = f2bf(tile[tx][i]);
}

// ---------------- GEMM: C = A[M][K](bf16) @ Bt[N][K](bf16)^T, fused epilogues ----------------
enum { EP_Q = 0, EP_K = 1, EP_V = 2, EP_WO = 3, EP_FFN1 = 4, EP_FFN2 = 5 };

template <int MODE>
__global__ __launch_bounds__(256) void gemm_kernel(
    const unsigned short* __restrict__ A,
    const unsigned short* __restrict__ Bt,
    int K, int N,
    const float* __restrict__ res,
    const float* __restrict__ bias,
    void* __restrict__ out)
{
  __shared__ unsigned short As[128 * 32];
  __shared__ unsigned short Bs[128 * 32];
  const int t = threadIdx.x;
  const int lane = t & 63;
  const int w = t >> 6;
  const int wr = w >> 1, wc = w & 1;
  const int c = lane & 15, g = lane >> 4;
  const long bm = (long)blockIdx.x * 128;
  const long bn = (long)blockIdx.y * 128;

  f32x4 acc[4][4];
  #pragma unroll
  for (int m = 0; m < 4; m++)
    #pragma unroll
    for (int n = 0; n < 4; n++) acc[m][n] = (f32x4){0.f, 0.f, 0.f, 0.f};

  const int srow = t >> 2;
  const int scol = (t & 3) * 8;
  const unsigned short* gA0 = A  + (bm + srow)      * (long)K + scol;
  const unsigned short* gA1 = A  + (bm + srow + 64) * (long)K + scol;
  const unsigned short* gB0 = Bt + (bn + srow)      * (long)K + scol;
  const unsigned short* gB1 = Bt + (bn + srow + 64) * (long)K + scol;
  unsigned short* lA0 = &As[w * 512];
  unsigned short* lA1 = &As[2048 + w * 512];
  unsigned short* lB0 = &Bs[w * 512];
  unsigned short* lB1 = &Bs[2048 + w * 512];

  for (int k0 = 0; k0 < K; k0 += 32) {
    __syncthreads();
    gload16(gA0 + k0, lA0);
    gload16(gA1 + k0, lA1);
    gload16(gB0 + k0, lB0);
    gload16(gB1 + k0, lB1);
    __syncthreads();
    bf16x8 af[4], bfr[4];
    #pragma unroll
    for (int m = 0; m < 4; m++)
      af[m] = *(const bf16x8*)&As[(wr*64 + m*16 + c) * 32 + g*8];
    #pragma unroll
    for (int n = 0; n < 4; n++)
      bfr[n] = *(const bf16x8*)&Bs[(wc*64 + n*16 + c) * 32 + g*8];
    #pragma unroll
    for (int m = 0; m < 4; m++)
      #pragma unroll
      for (int n = 0; n < 4; n++)
        acc[m][n] = __builtin_amdgcn_mfma_f32_16x16x32_bf16(af[m], bfr[n], acc[m][n], 0, 0, 0);
  }

  #pragma unroll
  for (int m = 0; m < 4; m++) {
    const long row0 = bm + wr*64 + m*16 + g*4;
    #pragma unroll
    for (int n = 0; n < 4; n++) {
      const long col = bn + wc*64 + n*16 + c;
      #pragma unroll
      for (int r = 0; r < 4; r++) {
        const long row = row0 + r;
        float v = acc[m][n][r];
        if constexpr (MODE == EP_Q) {
          // scale by 1/sqrt(HD), scatter to [B,H,S,D]
          ((unsigned short*)out)[(((row >> 11) * NH + (col >> 7)) * (long)SEQ + (row & 2047)) * HD + (col & 127)] =
              f2bf(v * 0.08838834764831845f);
        } else if constexpr (MODE == EP_K) {
          ((unsigned short*)out)[(((row >> 11) * NH + (col >> 7)) * (long)SEQ + (row & 2047)) * HD + (col & 127)] = f2bf(v);
        } else if constexpr (MODE == EP_V) {
          // scatter transposed to [B,H,D,S] for the PV B-operand
          ((unsigned short*)out)[(((row >> 11) * NH + (col >> 7)) * (long)HD + (col & 127)) * SEQ + (row & 2047)] = f2bf(v);
        } else if constexpr (MODE == EP_WO) {
          ((float*)out)[row * DM + col] = res[row * DM + col] + v;
        } else if constexpr (MODE == EP_FFN1) {
          float tt = v + bias[col];
          ((unsigned short*)out)[row * (long)N + col] =
              f2bf(0.5f * tt * (1.0f + erff(tt * 0.70710678118654752f)));
        } else { // EP_FFN2
          ((float*)out)[row * DM + col] = res[row * DM + col] + v + bias[col];
        }
      }
    }
  }
}

// ---------------- Flash attention, causal + alibi ----------------
// Q,K: [B,H,S,D] bf16 (Q pre-scaled). Vt: [B,H,D,S] bf16. Out: [B,S,H*D] bf16.
// Work-balanced decomposition: strip = 16 q rows (128 strips per bh).
// Pair strip sA=127-p (long, ntA=17..32 kv-tiles of 64) with sB=p (short,
// ntB=1..16). Block = 2 waves: wave0 does A tiles [0,17); wave1 does A tiles
// [17,ntA) (0..15 tiles), dumps partial (m,s,O) to LDS, then does all of B
// (ntB tiles) and writes B. After the barrier wave0 merges A partials and
// writes A. Per-wave work = exactly 17 / exactly 16 tiles -> uniform across
// all 2048 blocks, no load-imbalance tail.
__device__ __forceinline__ void attn_strip_tiles(
    const unsigned short* __restrict__ Kp,
    const unsigned short* __restrict__ Vp,
    const float* __restrict__ Ap,       // alibi + h*SEQ*SEQ + qc*SEQ
    const bf16x8 qf[4], int qc,
    int t0, int t1,
    float& m_run, float& s_run, f32x4 oacc[8],
    int c, int g)
{
  for (int tt = t0; tt < t1; tt++) {
    const int kv0 = tt * 64;
    // ---- QK^T: 4 independent 16-wide score chains ----
    f32x4 sc[4];
    #pragma unroll
    for (int st = 0; st < 4; st++) sc[st] = (f32x4){0.f, 0.f, 0.f, 0.f};
    #pragma unroll
    for (int dt = 0; dt < 4; dt++)
      #pragma unroll
      for (int st = 0; st < 4; st++) {
        bf16x8 kf = *(const bf16x8*)(Kp + (size_t)(kv0 + st * 16 + c) * HD + dt * 32 + g * 8);
        sc[st] = __builtin_amdgcn_mfma_f32_16x16x32_bf16(kf, qf[dt], sc[st], 0, 0, 0);
      }

    // ---- alibi + causal mask ----
    float4 al[4];
    #pragma unroll
    for (int st = 0; st < 4; st++) al[st] = *(const float4*)(Ap + kv0 + st * 16 + g * 4);
    float scr[16];
    #pragma unroll
    for (int st = 0; st < 4; st++) {
      scr[st*4+0] = (kv0 + st*16 + g*4 + 0 > qc) ? -1e30f : sc[st][0] + al[st].x;
      scr[st*4+1] = (kv0 + st*16 + g*4 + 1 > qc) ? -1e30f : sc[st][1] + al[st].y;
      scr[st*4+2] = (kv0 + st*16 + g*4 + 2 > qc) ? -1e30f : sc[st][2] + al[st].z;
      scr[st*4+3] = (kv0 + st*16 + g*4 + 3 > qc) ? -1e30f : sc[st][3] + al[st].w;
    }

    // ---- online softmax over 64 kv ----
    float tm = scr[0];
    #pragma unroll
    for (int i = 1; i < 16; i++) tm = fmaxf(tm, scr[i]);
    tm = fmaxf(tm, __shfl_xor(tm, 16));
    tm = fmaxf(tm, __shfl_xor(tm, 32));
    const float m_new = fmaxf(m_run, tm);
    const float corr = __expf(m_run - m_new);
    float pv[16]; float ps = 0.f;
    #pragma unroll
    for (int i = 0; i < 16; i++) { pv[i] = __expf(scr[i] - m_new); ps += pv[i]; }
    ps += __shfl_xor(ps, 16);
    ps += __shfl_xor(ps, 32);
    s_run = s_run * corr + ps;
    m_run = m_new;

    short4_t pf[4];
    #pragma unroll
    for (int st = 0; st < 4; st++) {
      pf[st][0] = (short)f2bf(pv[st*4+0]); pf[st][1] = (short)f2bf(pv[st*4+1]);
      pf[st][2] = (short)f2bf(pv[st*4+2]); pf[st][3] = (short)f2bf(pv[st*4+3]);
    }

    float cf[4];
    #pragma unroll
    for (int r = 0; r < 4; r++) cf[r] = __shfl(corr, g * 4 + r);

    // ---- PV: 8 independent output chains x 4 subtile MFMAs ----
    #pragma unroll
    for (int dt = 0; dt < 8; dt++) {
      f32x4 o = oacc[dt];
      o[0] *= cf[0]; o[1] *= cf[1]; o[2] *= cf[2]; o[3] *= cf[3];
      #pragma unroll
      for (int st = 0; st < 4; st++) {
        short4_t vf = *(const short4_t*)(Vp + (size_t)(dt * 16 + c) * SEQ + kv0 + st * 16 + g * 4);
        o = __builtin_amdgcn_mfma_f32_16x16x16bf16_1k(pf[st], vf, o, 0, 0, 0);
      }
      oacc[dt] = o;
    }
  }
}

__global__ __launch_bounds__(128) void attn_kernel(
    const unsigned short* __restrict__ Q,
    const unsigned short* __restrict__ Kg,
    const unsigned short* __restrict__ Vt,
    const float* __restrict__ alibi,
    unsigned short* __restrict__ Out)
{
  const int bh = blockIdx.x;
  const int h = bh & (NH - 1);
  const int b = bh >> 4;
  const int p = blockIdx.y;            // pair index 0..63
  const int wv = threadIdx.x >> 6;     // 0 or 1
  const int lane = threadIdx.x & 63;
  const int c = lane & 15, g = lane >> 4;

  const int sA = 127 - p;              // long strip
  const int sB = p;                    // short strip
  const int ntA = (sA >> 2) + 1;       // 17..32
  const int ntB = (sB >> 2) + 1;       // 1..16

  const unsigned short* Qp = Q  + (size_t)bh * SEQ * HD;
  const unsigned short* Kp = Kg + (size_t)bh * SEQ * HD;
  const unsigned short* Vp = Vt + (size_t)bh * HD * SEQ;
  const float* Ah = alibi + (size_t)h * SEQ * SEQ;

  __shared__ float lm[16], ls[16];
  __shared__ float lo[16][132];

  // ---------- phase 1: strip A (kv-split across the 2 waves) ----------
  {
    const int q0 = sA * 16, qc = q0 + c;
    bf16x8 qf[4];
    #pragma unroll
    for (int dt = 0; dt < 4; dt++)
      qf[dt] = *(const bf16x8*)(Qp + (size_t)qc * HD + dt * 32 + g * 8);
    f32x4 oacc[8];
    #pragma unroll
    for (int d = 0; d < 8; d++) oacc[d] = (f32x4){0.f, 0.f, 0.f, 0.f};
    float m_run = -1e30f, s_run = 0.f;

    const int t0 = wv ? 17 : 0;
    const int t1 = wv ? ntA : 17;
    attn_strip_tiles(Kp, Vp, Ah + (size_t)qc * SEQ, qf, qc, t0, t1, m_run, s_run, oacc, c, g);

    if (wv == 1) {
      if (g == 0) { lm[c] = m_run; ls[c] = s_run; }
      #pragma unroll
      for (int dt = 0; dt < 8; dt++)
        #pragma unroll
        for (int r = 0; r < 4; r++)
          lo[g * 4 + r][dt * 16 + c] = oacc[dt][r];
    }
    __syncthreads();
    if (wv == 0) {
      const float m1 = lm[c], s1 = ls[c];
      const float M = fmaxf(m_run, m1);
      const float e0 = __expf(m_run - M);
      const float e1 = __expf(m1 - M);
      const float sm = s_run * e0 + s1 * e1;
      float e0r[4], e1r[4], inv[4];
      #pragma unroll
      for (int r = 0; r < 4; r++) {
        e0r[r] = __shfl(e0, g * 4 + r);
        e1r[r] = __shfl(e1, g * 4 + r);
        inv[r] = 1.0f / __shfl(sm, g * 4 + r);
      }
      #pragma unroll
      for (int dt = 0; dt < 8; dt++)
        #pragma unroll
        for (int r = 0; r < 4; r++) {
          const float ov = oacc[dt][r] * e0r[r] + lo[g * 4 + r][dt * 16 + c] * e1r[r];
          Out[(size_t)(b * SEQ + q0 + g * 4 + r) * DM + h * HD + dt * 16 + c] =
              f2bf(ov * inv[r]);
        }
    }
  }

  // ---------- phase 2: wave1 alone does strip B (complete) ----------
  if (wv == 1) {
    const int q0 = sB * 16, qc = q0 + c;
    bf16x8 qf[4];
    #pragma unroll
    for (int dt = 0; dt < 4; dt++)
      qf[dt] = *(const bf16x8*)(Qp + (size_t)qc * HD + dt * 32 + g * 8);
    f32x4 oacc[8];
    #pragma unroll
    for (int d = 0; d < 8; d++) oacc[d] = (f32x4){0.f, 0.f, 0.f, 0.f};
    float m_run = -1e30f, s_run = 0.f;

    attn_strip_tiles(Kp, Vp, Ah + (size_t)qc * SEQ, qf, qc, 0, ntB, m_run, s_run, oacc, c, g);

    float inv[4];
    #pragma unroll
    for (int r = 0; r < 4; r++) inv[r] = 1.0f / __shfl(s_run, g * 4 + r);
    #pragma unroll
    for (int dt = 0; dt < 8; dt++)
      #pragma unroll
      for (int r = 0; r < 4; r++)
        Out[(size_t)(b * SEQ + q0 + g * 4 + r) * DM + h * HD + dt * 16 + c] =
            f2bf(oacc[dt][r] * inv[r]);
  }
}

// ---------------- launch ----------------
extern "C" void kernel_launch(void* const* d_in, const int* in_sizes, int n_in,
                              void* d_out, int out_size, void* d_ws, size_t ws_size,
                              hipStream_t stream) {
  const float* x     = (const float*)d_in[0];
  const float* alibi = (const float*)d_in[1];
  const float* Wq    = (const float*)d_in[2];
  const float* Wk    = (const float*)d_in[3];
  const float* Wv    = (const float*)d_in[4];
  const float* Wo    = (const float*)d_in[5];
  const float* ln1g  = (const float*)d_in[6];
  const float* ln1b  = (const float*)d_in[7];
  const float* ln2g  = (const float*)d_in[8];
  const float* ln2b  = (const float*)d_in[9];
  const float* w1    = (const float*)d_in[10];
  const float* b1    = (const float*)d_in[11];
  const float* w2    = (const float*)d_in[12];
  const float* b2    = (const float*)d_in[13];

  char* ws = (char*)d_ws;
  float*          hbuf = (float*)(ws);                                // 32MB f32 h
  unsigned short* xn   = (unsigned short*)(ws + (32ull  << 20));      // 16MB bf16 (xn, later n2)
  unsigned short* qb   = (unsigned short*)(ws + (48ull  << 20));      // 16MB
  unsigned short* kb   = (unsigned short*)(ws + (64ull  << 20));      // 16MB
  unsigned short* vt   = (unsigned short*)(ws + (80ull  << 20));      // 16MB
  unsigned short* ao   = (unsigned short*)(ws + (96ull  << 20));      // 16MB attn_out
  unsigned short* wt   = (unsigned short*)(ws + (112ull << 20));      // 32MB weight scratch
  unsigned short* a1   = (unsigned short*)(ws + (48ull  << 20));      // 64MB (reuses q/k/vt/ao)

  dim3 blk(256);
  dim3 tb(32, 8);

  ln_kernel<<<MROWS, blk, 0, stream>>>(x, ln1g, ln1b, xn);

  transpose_kernel<<<dim3(DM/32, DM/32), tb, 0, stream>>>(Wq, wt, DM, DM);
  gemm_kernel<EP_Q><<<dim3(MROWS/128, DM/128), blk, 0, stream>>>(xn, wt, DM, DM, nullptr, nullptr, qb);
  transpose_kernel<<<dim3(DM/32, DM/32), tb, 0, stream>>>(Wk, wt, DM, DM);
  gemm_kernel<EP_K><<<dim3(MROWS/128, DM/128), blk, 0, stream>>>(xn, wt, DM, DM, nullptr, nullptr, kb);
  transpose_kernel<<<dim3(DM/32, DM/32), tb, 0, stream>>>(Wv, wt, DM, DM);
  gemm_kernel<EP_V><<<dim3(MROWS/128, DM/128), blk, 0, stream>>>(xn, wt, DM, DM, nullptr, nullptr, vt);

  attn_kernel<<<dim3(NH * 2, 64), dim3(128), 0, stream>>>(qb, kb, vt, alibi, ao);

  transpose_kernel<<<dim3(DM/32, DM/32), tb, 0, stream>>>(Wo, wt, DM, DM);
  gemm_kernel<EP_WO><<<dim3(MROWS/128, DM/128), blk, 0, stream>>>(ao, wt, DM, DM, x, nullptr, hbuf);

  ln_kernel<<<MROWS, blk, 0, stream>>>(hbuf, ln2g, ln2b, xn);

  transpose_kernel<<<dim3(DFF/32, DM/32), tb, 0, stream>>>(w1, wt, DM, DFF);
  gemm_kernel<EP_FFN1><<<dim3(MROWS/128, DFF/128), blk, 0, stream>>>(xn, wt, DM, DFF, nullptr, b1, a1);

  transpose_kernel<<<dim3(DM/32, DFF/32), tb, 0, stream>>>(w2, wt, DFF, DM);
  gemm_kernel<EP_FFN2><<<dim3(MROWS/128, DM/128), blk, 0, stream>>>(a1, wt, DFF, DM, hbuf, b2, (float*)d_out);
}

// Round 4
// 825.964 us; speedup vs baseline: 1.3411x; 1.3411x over previous
//
#include <hip/hip_runtime.h>
#include <math.h>

#define DM   2048
#define DFF  8192
#define NH   16
#define HD   128
#define SEQ  2048
#define MROWS 4096   // BATCH * SEQ

typedef __attribute__((ext_vector_type(4))) float  f32x4;
typedef __attribute__((ext_vector_type(8))) __bf16 bf16x8;
typedef __attribute__((ext_vector_type(4))) short  short4_t;

__device__ inline unsigned short f2bf(float f) {
  union { float f; unsigned int u; } x; x.f = f;
  unsigned int r = x.u + 0x7FFFu + ((x.u >> 16) & 1u);
  return (unsigned short)(r >> 16);
}

__device__ inline void gload16(const void* g, void* l) {
  __builtin_amdgcn_global_load_lds(
      (const __attribute__((address_space(1))) unsigned int*)g,
      (__attribute__((address_space(3))) unsigned int*)l, 16, 0, 0);
}

// ---------------- LayerNorm (f32 in, bf16 out) ----------------
__global__ __launch_bounds__(256) void ln_kernel(
    const float* __restrict__ in, const float* __restrict__ gw,
    const float* __restrict__ bw, unsigned short* __restrict__ out)
{
  const int row = blockIdx.x;
  const float* xr = in + (size_t)row * DM;
  const int t = threadIdx.x, lane = t & 63, w = t >> 6;
  float4 v0 = ((const float4*)xr)[t];
  float4 v1 = ((const float4*)xr)[t + 256];
  float s = v0.x+v0.y+v0.z+v0.w + v1.x+v1.y+v1.z+v1.w;
  float s2 = v0.x*v0.x+v0.y*v0.y+v0.z*v0.z+v0.w*v0.w
           + v1.x*v1.x+v1.y*v1.y+v1.z*v1.z+v1.w*v1.w;
  #pragma unroll
  for (int off = 32; off; off >>= 1) { s += __shfl_xor(s, off); s2 += __shfl_xor(s2, off); }
  __shared__ float rs[4], rs2[4];
  if (lane == 0) { rs[w] = s; rs2[w] = s2; }
  __syncthreads();
  s = rs[0] + rs[1] + rs[2] + rs[3];
  s2 = rs2[0] + rs2[1] + rs2[2] + rs2[3];
  const float mu = s * (1.0f / DM);
  const float var = s2 * (1.0f / DM) - mu * mu;
  const float rstd = rsqrtf(var + 1e-5f);
  float4 g0 = ((const float4*)gw)[t],     b0 = ((const float4*)bw)[t];
  float4 g1 = ((const float4*)gw)[t+256], b1 = ((const float4*)bw)[t+256];
  unsigned short* o = out + (size_t)row * DM;
  int i0 = t * 4, i1 = (t + 256) * 4;
  o[i0+0] = f2bf((v0.x-mu)*rstd*g0.x + b0.x);
  o[i0+1] = f2bf((v0.y-mu)*rstd*g0.y + b0.y);
  o[i0+2] = f2bf((v0.z-mu)*rstd*g0.z + b0.z);
  o[i0+3] = f2bf((v0.w-mu)*rstd*g0.w + b0.w);
  o[i1+0] = f2bf((v1.x-mu)*rstd*g1.x + b1.x);
  o[i1+1] = f2bf((v1.y-mu)*rstd*g1.y + b1.y);
  o[i1+2] = f2bf((v1.z-mu)*rstd*g1.z + b1.z);
  o[i1+3] = f2bf((v1.w-mu)*rstd*g1.w + b1.w);
}

// ------- weight transpose + f32->bf16: in[nrows][ncols] -> out[ncols][nrows] -------
__global__ void transpose_kernel(const float* __restrict__ in,
                                 unsigned short* __restrict__ out,
                                 int nrows, int ncols)
{
  __shared__ float tile[32][33];
  const int bx = blockIdx.x * 32;  // col base
  const int by = blockIdx.y * 32;  // row base
  const int tx = threadIdx.x, ty = threadIdx.y;
  #pragma unroll
  for (int i = ty; i < 32; i += 8)
    tile[i][tx] = in[(size_t)(by + i) * ncols + bx + tx];
  __syncthreads();
  #pragma unroll
  for (int i = ty; i < 32; i += 8)
    out[(size_t)(bx + i) * nrows + by + tx] = f2bf(tile[tx][i]);
}

// ---------------- GEMM: C = A[M][K](bf16) @ Bt[N][K](bf16)^T, fused epilogues ----------------
enum { EP_Q = 0, EP_K = 1, EP_V = 2, EP_WO = 3, EP_FFN1 = 4, EP_FFN2 = 5 };

template <int MODE>
__global__ __launch_bounds__(256) void gemm_kernel(
    const unsigned short* __restrict__ A,
    const unsigned short* __restrict__ Bt,
    int K, int N,
    const float* __restrict__ res,
    const float* __restrict__ bias,
    void* __restrict__ out)
{
  __shared__ unsigned short As[128 * 32];
  __shared__ unsigned short Bs[128 * 32];
  const int t = threadIdx.x;
  const int lane = t & 63;
  const int w = t >> 6;
  const int wr = w >> 1, wc = w & 1;
  const int c = lane & 15, g = lane >> 4;
  const long bm = (long)blockIdx.x * 128;
  const long bn = (long)blockIdx.y * 128;

  f32x4 acc[4][4];
  #pragma unroll
  for (int m = 0; m < 4; m++)
    #pragma unroll
    for (int n = 0; n < 4; n++) acc[m][n] = (f32x4){0.f, 0.f, 0.f, 0.f};

  const int srow = t >> 2;
  const int scol = (t & 3) * 8;
  const unsigned short* gA0 = A  + (bm + srow)      * (long)K + scol;
  const unsigned short* gA1 = A  + (bm + srow + 64) * (long)K + scol;
  const unsigned short* gB0 = Bt + (bn + srow)      * (long)K + scol;
  const unsigned short* gB1 = Bt + (bn + srow + 64) * (long)K + scol;
  unsigned short* lA0 = &As[w * 512];
  unsigned short* lA1 = &As[2048 + w * 512];
  unsigned short* lB0 = &Bs[w * 512];
  unsigned short* lB1 = &Bs[2048 + w * 512];

  for (int k0 = 0; k0 < K; k0 += 32) {
    __syncthreads();
    gload16(gA0 + k0, lA0);
    gload16(gA1 + k0, lA1);
    gload16(gB0 + k0, lB0);
    gload16(gB1 + k0, lB1);
    __syncthreads();
    bf16x8 af[4], bfr[4];
    #pragma unroll
    for (int m = 0; m < 4; m++)
      af[m] = *(const bf16x8*)&As[(wr*64 + m*16 + c) * 32 + g*8];
    #pragma unroll
    for (int n = 0; n < 4; n++)
      bfr[n] = *(const bf16x8*)&Bs[(wc*64 + n*16 + c) * 32 + g*8];
    #pragma unroll
    for (int m = 0; m < 4; m++)
      #pragma unroll
      for (int n = 0; n < 4; n++)
        acc[m][n] = __builtin_amdgcn_mfma_f32_16x16x32_bf16(af[m], bfr[n], acc[m][n], 0, 0, 0);
  }

  #pragma unroll
  for (int m = 0; m < 4; m++) {
    const long row0 = bm + wr*64 + m*16 + g*4;
    #pragma unroll
    for (int n = 0; n < 4; n++) {
      const long col = bn + wc*64 + n*16 + c;
      #pragma unroll
      for (int r = 0; r < 4; r++) {
        const long row = row0 + r;
        float v = acc[m][n][r];
        if constexpr (MODE == EP_Q) {
          // scale by 1/sqrt(HD), scatter to [B,H,S,D]
          ((unsigned short*)out)[(((row >> 11) * NH + (col >> 7)) * (long)SEQ + (row & 2047)) * HD + (col & 127)] =
              f2bf(v * 0.08838834764831845f);
        } else if constexpr (MODE == EP_K) {
          ((unsigned short*)out)[(((row >> 11) * NH + (col >> 7)) * (long)SEQ + (row & 2047)) * HD + (col & 127)] = f2bf(v);
        } else if constexpr (MODE == EP_V) {
          // scatter transposed to [B,H,D,S] for the PV B-operand
          ((unsigned short*)out)[(((row >> 11) * NH + (col >> 7)) * (long)HD + (col & 127)) * SEQ + (row & 2047)] = f2bf(v);
        } else if constexpr (MODE == EP_WO) {
          ((float*)out)[row * DM + col] = res[row * DM + col] + v;
        } else if constexpr (MODE == EP_FFN1) {
          float tt = v + bias[col];
          ((unsigned short*)out)[row * (long)N + col] =
              f2bf(0.5f * tt * (1.0f + erff(tt * 0.70710678118654752f)));
        } else { // EP_FFN2
          ((float*)out)[row * DM + col] = res[row * DM + col] + v + bias[col];
        }
      }
    }
  }
}

// ---------------- Flash attention, causal + alibi, LDS-staged K/V ----------------
// Q,K: [B,H,S,D] bf16 (Q pre-scaled). Vt: [B,H,D,S] bf16. Out: [B,S,H*D] bf16.
// Block = 4 waves = 64 q rows (wave w owns 16). Block processes the chunk pair
// (j, 31-j) -> uniform 33 kv-tiles per block. Per kv-tile (64 kv): K-tile
// [64][128]b16 (16KB) + V-tile [128][64]b16 (16KB) staged in LDS via
// global_load_lds (linear dest + inverse-swizzled SOURCE; reads use the same
// XOR ^((row&7)<<4) -> involution, rule #21). Double-buffered: stage(next)
// issued BEFORE compute(cur); one __syncthreads per tile (drains vmcnt).
__global__ __launch_bounds__(256) void attn_kernel(
    const unsigned short* __restrict__ Q,
    const unsigned short* __restrict__ Kg,
    const unsigned short* __restrict__ Vt,
    const float* __restrict__ alibi,
    unsigned short* __restrict__ Out)
{
  __shared__ unsigned short lds[2][16384];   // 2 x (16KB K | 16KB V)

  const int bh = blockIdx.x;
  const int h = bh & (NH - 1);
  const int b = bh >> 4;
  const int j = blockIdx.y;                  // pair 0..15
  const int t = threadIdx.x;
  const int w = t >> 6;                      // wave 0..3
  const int lane = t & 63;
  const int c = lane & 15, g = lane >> 4;
  const int cx = (c & 7) << 4;               // read-side XOR swizzle

  const char* KpB = (const char*)(Kg + (size_t)bh * SEQ * HD);
  const char* VpB = (const char*)(Vt + (size_t)bh * SEQ * HD);
  const unsigned short* Qp = Q + (size_t)bh * SEQ * HD;
  const float* Ah = alibi + (size_t)h * SEQ * SEQ;

  #pragma unroll 1
  for (int half = 0; half < 2; half++) {
    const int cidx = half ? (31 - j) : j;
    const int nt = cidx + 1;                 // kv tiles for this chunk
    const int qb = cidx * 64;
    const int q0 = qb + w * 16, qc = q0 + c;

    bf16x8 qf[4];
    #pragma unroll
    for (int dt = 0; dt < 4; dt++)
      qf[dt] = *(const bf16x8*)(Qp + (size_t)qc * HD + dt * 32 + g * 8);

    f32x4 oacc[8];
    #pragma unroll
    for (int d = 0; d < 8; d++) oacc[d] = (f32x4){0.f, 0.f, 0.f, 0.f};
    float m_run = -1e30f, s_run = 0.f;
    const float* Ap = Ah + (size_t)qc * SEQ;

    // ---- staging: waves 0-1 -> K region [0,16KB), waves 2-3 -> V [16KB,32KB)
    auto stage = [&](int tt, unsigned short* dst) {
      const size_t kvo = (size_t)tt * 64;
      #pragma unroll
      for (int k = 0; k < 8; k++) {
        const int o = w * 8192 + k * 1024 + lane * 16;
        if (w < 2) {
          const int so = o ^ (((o >> 8) & 7) << 4);        // inverse swizzle (involution)
          gload16(KpB + kvo * 256 + so, dst + ((w * 8192 + k * 1024) >> 1));
        } else {
          const int o2 = o - 16384;
          const int d = o2 >> 7, win = o2 & 127;
          gload16(VpB + (size_t)d * 4096 + kvo * 2 + (win ^ ((d & 7) << 4)),
                  dst + ((w * 8192 + k * 1024) >> 1));
        }
      }
    };

    stage(0, lds[0]);
    __syncthreads();
    int buf = 0;

    for (int tt = 0; tt < nt; tt++) {
      if (tt + 1 < nt) stage(tt + 1, lds[buf ^ 1]);
      const unsigned short* LK = lds[buf];
      const unsigned short* LV = lds[buf] + 8192;
      const int kv0 = tt * 64;

      // ---- QK^T from LDS: 4 independent 16-wide score chains ----
      f32x4 sc[4];
      #pragma unroll
      for (int st = 0; st < 4; st++) sc[st] = (f32x4){0.f, 0.f, 0.f, 0.f};
      #pragma unroll
      for (int dt = 0; dt < 4; dt++)
        #pragma unroll
        for (int st = 0; st < 4; st++) {
          bf16x8 kf = *(const bf16x8*)&LK[(st * 4096 + c * 256 + ((dt * 64 + g * 16) ^ cx)) >> 1];
          sc[st] = __builtin_amdgcn_mfma_f32_16x16x32_bf16(kf, qf[dt], sc[st], 0, 0, 0);
        }

      // ---- alibi + causal mask ----
      float4 al[4];
      #pragma unroll
      for (int st = 0; st < 4; st++) al[st] = *(const float4*)(Ap + kv0 + st * 16 + g * 4);
      float scr[16];
      #pragma unroll
      for (int st = 0; st < 4; st++) {
        scr[st*4+0] = (kv0 + st*16 + g*4 + 0 > qc) ? -1e30f : sc[st][0] + al[st].x;
        scr[st*4+1] = (kv0 + st*16 + g*4 + 1 > qc) ? -1e30f : sc[st][1] + al[st].y;
        scr[st*4+2] = (kv0 + st*16 + g*4 + 2 > qc) ? -1e30f : sc[st][2] + al[st].z;
        scr[st*4+3] = (kv0 + st*16 + g*4 + 3 > qc) ? -1e30f : sc[st][3] + al[st].w;
      }

      // ---- online softmax over 64 kv ----
      float tm = scr[0];
      #pragma unroll
      for (int i = 1; i < 16; i++) tm = fmaxf(tm, scr[i]);
      tm = fmaxf(tm, __shfl_xor(tm, 16));
      tm = fmaxf(tm, __shfl_xor(tm, 32));
      const float m_new = fmaxf(m_run, tm);
      const float corr = __expf(m_run - m_new);
      float pv[16]; float ps = 0.f;
      #pragma unroll
      for (int i = 0; i < 16; i++) { pv[i] = __expf(scr[i] - m_new); ps += pv[i]; }
      ps += __shfl_xor(ps, 16);
      ps += __shfl_xor(ps, 32);
      s_run = s_run * corr + ps;
      m_run = m_new;

      short4_t pf[4];
      #pragma unroll
      for (int st = 0; st < 4; st++) {
        pf[st][0] = (short)f2bf(pv[st*4+0]); pf[st][1] = (short)f2bf(pv[st*4+1]);
        pf[st][2] = (short)f2bf(pv[st*4+2]); pf[st][3] = (short)f2bf(pv[st*4+3]);
      }

      float cf[4];
      #pragma unroll
      for (int r = 0; r < 4; r++) cf[r] = __shfl(corr, g * 4 + r);

      // ---- PV from LDS: 8 output chains x 4 subtile MFMAs ----
      #pragma unroll
      for (int dt = 0; dt < 8; dt++) {
        f32x4 o = oacc[dt];
        o[0] *= cf[0]; o[1] *= cf[1]; o[2] *= cf[2]; o[3] *= cf[3];
        #pragma unroll
        for (int st = 0; st < 4; st++) {
          short4_t vf = *(const short4_t*)&LV[((dt * 16 + c) * 128 + ((st * 32 + g * 8) ^ cx)) >> 1];
          o = __builtin_amdgcn_mfma_f32_16x16x16bf16_1k(pf[st], vf, o, 0, 0, 0);
        }
        oacc[dt] = o;
      }

      __syncthreads();   // drains this iter's stage (vmcnt) + read-complete for buf
      buf ^= 1;
    }

    // ---- epilogue ----
    float inv[4];
    #pragma unroll
    for (int r = 0; r < 4; r++) inv[r] = 1.0f / __shfl(s_run, g * 4 + r);
    #pragma unroll
    for (int dt = 0; dt < 8; dt++)
      #pragma unroll
      for (int r = 0; r < 4; r++)
        Out[(size_t)(b * SEQ + q0 + g * 4 + r) * DM + h * HD + dt * 16 + c] =
            f2bf(oacc[dt][r] * inv[r]);
  }
}

// ---------------- launch ----------------
extern "C" void kernel_launch(void* const* d_in, const int* in_sizes, int n_in,
                              void* d_out, int out_size, void* d_ws, size_t ws_size,
                              hipStream_t stream) {
  const float* x     = (const float*)d_in[0];
  const float* alibi = (const float*)d_in[1];
  const float* Wq    = (const float*)d_in[2];
  const float* Wk    = (const float*)d_in[3];
  const float* Wv    = (const float*)d_in[4];
  const float* Wo    = (const float*)d_in[5];
  const float* ln1g  = (const float*)d_in[6];
  const float* ln1b  = (const float*)d_in[7];
  const float* ln2g  = (const float*)d_in[8];
  const float* ln2b  = (const float*)d_in[9];
  const float* w1    = (const float*)d_in[10];
  const float* b1    = (const float*)d_in[11];
  const float* w2    = (const float*)d_in[12];
  const float* b2    = (const float*)d_in[13];

  char* ws = (char*)d_ws;
  float*          hbuf = (float*)(ws);                                // 32MB f32 h
  unsigned short* xn   = (unsigned short*)(ws + (32ull  << 20));      // 16MB bf16 (xn, later n2)
  unsigned short* qb   = (unsigned short*)(ws + (48ull  << 20));      // 16MB
  unsigned short* kb   = (unsigned short*)(ws + (64ull  << 20));      // 16MB
  unsigned short* vt   = (unsigned short*)(ws + (80ull  << 20));      // 16MB
  unsigned short* ao   = (unsigned short*)(ws + (96ull  << 20));      // 16MB attn_out
  unsigned short* wt   = (unsigned short*)(ws + (112ull << 20));      // 32MB weight scratch
  unsigned short* a1   = (unsigned short*)(ws + (48ull  << 20));      // 64MB (reuses q/k/vt/ao)

  dim3 blk(256);
  dim3 tb(32, 8);

  ln_kernel<<<MROWS, blk, 0, stream>>>(x, ln1g, ln1b, xn);

  transpose_kernel<<<dim3(DM/32, DM/32), tb, 0, stream>>>(Wq, wt, DM, DM);
  gemm_kernel<EP_Q><<<dim3(MROWS/128, DM/128), blk, 0, stream>>>(xn, wt, DM, DM, nullptr, nullptr, qb);
  transpose_kernel<<<dim3(DM/32, DM/32), tb, 0, stream>>>(Wk, wt, DM, DM);
  gemm_kernel<EP_K><<<dim3(MROWS/128, DM/128), blk, 0, stream>>>(xn, wt, DM, DM, nullptr, nullptr, kb);
  transpose_kernel<<<dim3(DM/32, DM/32), tb, 0, stream>>>(Wv, wt, DM, DM);
  gemm_kernel<EP_V><<<dim3(MROWS/128, DM/128), blk, 0, stream>>>(xn, wt, DM, DM, nullptr, nullptr, vt);

  attn_kernel<<<dim3(NH * 2, 16), blk, 0, stream>>>(qb, kb, vt, alibi, ao);

  transpose_kernel<<<dim3(DM/32, DM/32), tb, 0, stream>>>(Wo, wt, DM, DM);
  gemm_kernel<EP_WO><<<dim3(MROWS/128, DM/128), blk, 0, stream>>>(ao, wt, DM, DM, x, nullptr, hbuf);

  ln_kernel<<<MROWS, blk, 0, stream>>>(hbuf, ln2g, ln2b, xn);

  transpose_kernel<<<dim3(DFF/32, DM/32), tb, 0, stream>>>(w1, wt, DM, DFF);
  gemm_kernel<EP_FFN1><<<dim3(MROWS/128, DFF/128), blk, 0, stream>>>(xn, wt, DM, DFF, nullptr, b1, a1);

  transpose_kernel<<<dim3(DM/32, DFF/32), tb, 0, stream>>>(w2, wt, DFF, DM);
  gemm_kernel<EP_FFN2><<<dim3(MROWS/128, DM/128), blk, 0, stream>>>(a1, wt, DFF, DM, hbuf, b2, (float*)d_out);
}